// Round 4
// baseline (107.480 us; speedup 1.0000x reference)
//
#include <hip/hip_runtime.h>

// out[b, t] = x[b] * r^t,  r = 1.0 + (0.99 - 1.0) * delta_t  (f64 -> f32).
// Output layout: (B, steps, 1) row-major fp32 -> out[b*steps + t].
//
// Write-BW-bound (512 MiB stored). Ladder: R1 4.8 TB/s; R2 float4 rows 5.54;
// R3 non-NT neutral 5.61. Fill kernel reference: 6.85 TB/s at ~10.7% occupancy
// with long linear per-wave streams. R4: mimic fill — 1 block/CU (4 waves/CU),
// each wave owns a contiguous 32-row (512 KiB) slab and walks it linearly with
// 1 KiB wave-bursts; x-load is wave-uniform scalar; per-lane scale updated by
// one f32 mul per store (reset every row, no drift).

typedef float vfloat4 __attribute__((ext_vector_type(4)));

__global__ __launch_bounds__(256) void air_res_stream(
    const float* __restrict__ x,
    const float* __restrict__ dt_p,
    float* __restrict__ out,
    int B, int steps, int rpw)       // rows per wave
{
    const int lane = threadIdx.x & 63;
    const int wv   = threadIdx.x >> 6;                       // wave in block
    const int wpb  = blockDim.x >> 6;
    const long long gw = (long long)blockIdx.x * wpb + wv;   // global wave id

    const double COEF = 0.99 - 1.0;                          // exact ref const
    const double rd   = 1.0 + COEF * (double)dt_p[0];
    const double l2r  = log2(rd);
    const float  rf   = (float)rd;
    const float  r2   = (float)(rd * rd);
    const float  r3   = (float)(rd * rd * rd);
    // per-lane base scale r^(4*lane), and per-iter step r^256 — both via f64.
    const float  s_lane = (float)exp2((double)(4 * lane) * l2r);
    const float  rstep  = (float)exp2((double)256.0 * l2r);
    const int    iters  = steps >> 8;                        // steps/256

    int row = (int)(gw * rpw);
    const int row_end = row + rpw;
    for (; row < row_end; ++row) {
        const float xb = x[row];                 // wave-uniform -> s_load
        float xs = xb * s_lane;                  // x[b] * r^(4*lane)
        float* p = out + (long long)row * steps + 4 * lane;
#pragma unroll 4
        for (int i = 0; i < iters; ++i) {
            *(vfloat4*)p = (vfloat4){xs, xs * rf, xs * r2, xs * r3};
            xs *= rstep;                         // advance t by 256
            p  += 256;
        }
    }
}

// Generic scalar fallback (any shape). One element per thread, grid-stride.
__global__ __launch_bounds__(256) void air_res_scalar(
    const float* __restrict__ x,
    const float* __restrict__ dt_p,
    float* __restrict__ out,
    int B, int steps)
{
    const long long total    = (long long)B * steps;
    const long long nthreads = (long long)gridDim.x * blockDim.x;
    const double COEF = 0.99 - 1.0;
    const double rd   = 1.0 + COEF * (double)dt_p[0];
    const double l2r  = log2(rd);

    for (long long i = (long long)blockIdx.x * blockDim.x + threadIdx.x;
         i < total; i += nthreads) {
        const int b = (int)(i / steps);
        const int t = (int)(i % steps);
        out[i] = x[b] * (float)exp2((double)t * l2r);
    }
}

extern "C" void kernel_launch(void* const* d_in, const int* in_sizes, int n_in,
                              void* d_out, int out_size, void* d_ws, size_t ws_size,
                              hipStream_t stream) {
    // Inputs (setup_inputs order): steps (scalar, unused on host side),
    // x (float32, B elements), delta_t (float32 scalar, on device).
    const float* x    = (const float*)d_in[1];
    const float* dt_p = (const float*)d_in[2];
    float* out        = (float*)d_out;

    const int B     = in_sizes[1];
    const int steps = out_size / B;   // 4096

    const int threads = 256;
    const int blocks  = 256;          // 1 block/CU, 4 waves/CU (fill-like)
    const int nwaves  = blocks * (threads / 64);   // 1024

    if ((steps % 256) == 0 && (B % nwaves) == 0) {
        air_res_stream<<<blocks, threads, 0, stream>>>(
            x, dt_p, out, B, steps, B / nwaves);
    } else {
        air_res_scalar<<<2048, threads, 0, stream>>>(x, dt_p, out, B, steps);
    }
}